// Round 3
// baseline (4768.513 us; speedup 1.0000x reference)
//
#include <hip/hip_runtime.h>

#define BB 8
#define CC 512
#define NN 4096
#define GG 32
#define EPSV 1e-5f
#define SCALE 0.044194173824159216f  // 1/sqrt(512)

// per-batch u16 offsets in workspace: [q-nat | k-nat | qTf | kTf | vf], 20MB/batch
#define QN 0u
#define KN 2097152u
#define QTF 4194304u
#define KTF 6291456u
#define VF 8388608u
#define BSTR 10485760u

typedef unsigned short u16;
typedef unsigned int u32;
typedef unsigned long long u64;
typedef __attribute__((ext_vector_type(8))) short bf16x8;
typedef __attribute__((ext_vector_type(4))) float f32x4;

__device__ __forceinline__ u16 f2bf(float f) {
  u32 u = __float_as_uint(f);
  u32 r = (u + 0x7FFFu + ((u >> 16) & 1u)) >> 16;  // RNE
  return (u16)r;
}

__device__ __forceinline__ u64 pack4bf(float a, float b, float c, float d) {
  return (u64)f2bf(a) | ((u64)f2bf(b) << 16) | ((u64)f2bf(c) << 32) | ((u64)f2bf(d) << 48);
}

// ---------------- GroupNorm statistics ----------------
__global__ __launch_bounds__(256) void gn_stats_kernel(const float* __restrict__ x,
                                                       float* __restrict__ stats) {
  const int bg = blockIdx.x;
  const float4* xp = (const float4*)(x + (size_t)bg * 16 * NN);
  const int n4 = 16 * NN / 4;
  float s = 0.f, ss = 0.f;
  for (int i = threadIdx.x; i < n4; i += 256) {
    float4 v = xp[i];
    s += v.x + v.y + v.z + v.w;
    ss += v.x * v.x + v.y * v.y + v.z * v.z + v.w * v.w;
  }
  for (int off = 32; off > 0; off >>= 1) {
    s += __shfl_down(s, off, 64);
    ss += __shfl_down(ss, off, 64);
  }
  __shared__ float rs[4], rss[4];
  const int wid = threadIdx.x >> 6, lane = threadIdx.x & 63;
  if (lane == 0) { rs[wid] = s; rss[wid] = ss; }
  __syncthreads();
  if (threadIdx.x == 0) {
    float S = rs[0] + rs[1] + rs[2] + rs[3];
    float SS = rss[0] + rss[1] + rss[2] + rss[3];
    const float invn = 1.0f / (16.0f * NN);
    float mean = S * invn;
    float var = SS * invn - mean * mean;
    stats[bg * 2] = mean;
    stats[bg * 2 + 1] = rsqrtf(var + EPSV);
  }
}

// ------------- QKV GEMM + GroupNorm fused; q,k natural bf16; v frag-major -------------
__global__ __launch_bounds__(256) void qkv_gemm_kernel(
    const float* __restrict__ x, const float* __restrict__ gamma,
    const float* __restrict__ beta, const float* __restrict__ wqkv,
    const float* __restrict__ bqkv, const float* __restrict__ stats,
    u16* __restrict__ wsm) {
  __shared__ __align__(16) float Wt[16][68];
  __shared__ __align__(16) float Ht[16][68];
  const int b = blockIdx.z;
  const int o0 = blockIdx.y * 64;
  const int n0 = blockIdx.x * 64;
  const int t = threadIdx.x;
  const int to = (t >> 4) * 4;
  const int tn = (t & 15) * 4;
  const int wo = t >> 2;
  const int wk = (t & 3) * 4;
  const int xc = t >> 4;
  const int xn = (t & 15) * 4;
  const float* xb = x + (size_t)b * CC * NN;
  float acc[4][4] = {{0.f}};
  for (int kk = 0; kk < CC; kk += 16) {
    float4 wv = *(const float4*)(wqkv + (size_t)(o0 + wo) * CC + kk + wk);
    const int c = kk + xc;
    const int g = c >> 4;
    const float mean = stats[(b * GG + g) * 2];
    const float rstd = stats[(b * GG + g) * 2 + 1];
    const float aa = rstd * gamma[c];
    const float dd = beta[c] - mean * aa;
    float4 xv = *(const float4*)(xb + (size_t)c * NN + n0 + xn);
    __syncthreads();
    Wt[wk + 0][wo] = wv.x;
    Wt[wk + 1][wo] = wv.y;
    Wt[wk + 2][wo] = wv.z;
    Wt[wk + 3][wo] = wv.w;
    float4 hv;
    hv.x = fmaf(aa, xv.x, dd);
    hv.y = fmaf(aa, xv.y, dd);
    hv.z = fmaf(aa, xv.z, dd);
    hv.w = fmaf(aa, xv.w, dd);
    *(float4*)&Ht[xc][xn] = hv;
    __syncthreads();
#pragma unroll
    for (int k = 0; k < 16; ++k) {
      float4 w4 = *(const float4*)&Wt[k][to];
      float4 h4 = *(const float4*)&Ht[k][tn];
      acc[0][0] = fmaf(w4.x, h4.x, acc[0][0]);
      acc[0][1] = fmaf(w4.x, h4.y, acc[0][1]);
      acc[0][2] = fmaf(w4.x, h4.z, acc[0][2]);
      acc[0][3] = fmaf(w4.x, h4.w, acc[0][3]);
      acc[1][0] = fmaf(w4.y, h4.x, acc[1][0]);
      acc[1][1] = fmaf(w4.y, h4.y, acc[1][1]);
      acc[1][2] = fmaf(w4.y, h4.z, acc[1][2]);
      acc[1][3] = fmaf(w4.y, h4.w, acc[1][3]);
      acc[2][0] = fmaf(w4.z, h4.x, acc[2][0]);
      acc[2][1] = fmaf(w4.z, h4.y, acc[2][1]);
      acc[2][2] = fmaf(w4.z, h4.z, acc[2][2]);
      acc[2][3] = fmaf(w4.z, h4.w, acc[2][3]);
      acc[3][0] = fmaf(w4.w, h4.x, acc[3][0]);
      acc[3][1] = fmaf(w4.w, h4.y, acc[3][1]);
      acc[3][2] = fmaf(w4.w, h4.z, acc[3][2]);
      acc[3][3] = fmaf(w4.w, h4.w, acc[3][3]);
    }
  }
  u16* wb = wsm + (size_t)b * BSTR;
  if (o0 < 1024) {
    const u32 roff = (o0 < 512) ? QN : KN;
    const int lo0 = (o0 < 512) ? o0 : o0 - 512;
#pragma unroll
    for (int i = 0; i < 4; ++i) {
      const float bias = bqkv[o0 + to + i];
      u64 pk = pack4bf(acc[i][0] + bias, acc[i][1] + bias, acc[i][2] + bias, acc[i][3] + bias);
      *(u64*)(wb + roff + (size_t)(lo0 + to + i) * NN + n0 + tn) = pk;
    }
  } else {
    // V -> frag-major: B-frag layout [kj(128)][ct(32)] x 512 u16; lane=(c&15)+16*((j>>3)&3)
    const int j = n0 + tn;
#pragma unroll
    for (int i = 0; i < 4; ++i) {
      const int c = o0 - 1024 + to + i;
      const float bias = bqkv[o0 + to + i];
      u64 pk = pack4bf(acc[i][0] + bias, acc[i][1] + bias, acc[i][2] + bias, acc[i][3] + bias);
      const size_t frag = (size_t)(j >> 5) * 32 + (c >> 4);
      const int lane = (c & 15) + 16 * ((j >> 3) & 3);
      *(u64*)(wb + VF + frag * 512 + lane * 8 + (j & 7)) = pk;
    }
  }
}

// ------------- transpose + frag-pack q,k: [c][n] natural -> frag-major [ntile][kc] -------------
__global__ __launch_bounds__(256) void pack_qk_kernel(u16* __restrict__ wsm) {
  __shared__ __align__(16) u16 Ts[64 * 64];
  const int b = blockIdx.z >> 1;
  const int which = blockIdx.z & 1;
  const int c0 = blockIdx.y * 64;
  const int n0 = blockIdx.x * 64;
  const int t = threadIdx.x;
  const u16* src = wsm + (size_t)b * BSTR + (which ? KN : QN);
  u16* dst = wsm + (size_t)b * BSTR + (which ? KTF : QTF);
#pragma unroll
  for (int it = 0; it < 2; ++it) {
    const int U = it * 256 + t;
    const int r = U >> 3, cu = U & 7;
    const int pu = cu ^ ((r >> 3) & 7);
    *(uint4*)((char*)Ts + r * 128 + pu * 16) =
        *(const uint4*)(src + (size_t)(c0 + r) * NN + n0 + cu * 8);
  }
  __syncthreads();
#pragma unroll
  for (int it = 0; it < 2; ++it) {
    const int U = it * 256 + t;
    const int n = U & 63, cu2 = U >> 6;
    bf16x8 v;
#pragma unroll
    for (int jj = 0; jj < 8; ++jj) {
      const int c = cu2 * 8 + jj;
      v[jj] = (short)Ts[c * 64 + (((n >> 3) ^ cu2) << 3) + (n & 7)];
    }
    const int frag = ((n0 + n) >> 4) * 16 + (c0 >> 5) + (cu2 >> 2);
    const int lane = ((n0 + n) & 15) + 16 * (cu2 & 3);
    *(bf16x8*)(dst + (size_t)frag * 512 + lane * 8) = v;
  }
}

// ------------- MFMA flash attention, S-transposed, BQ=128, TK=64, 1024 threads -------------
__global__ __launch_bounds__(1024) void attn_mfma_kernel(u16* __restrict__ wsm) {
  __shared__ __align__(16) u16 Qf[65536];   // 128KB: 8 it-tiles x 16 kc x 512 u16
  __shared__ __align__(16) u16 Pf[8192];    // 16KB: 8 it x 2 kj x 512 u16
  __shared__ float mbuf[8][2][16];
  __shared__ float lbuf[8][2][16];
  __shared__ float alpha_s[128];
  __shared__ float invl_s[128];

  const int b = blockIdx.y;
  const int i0 = blockIdx.x * 128;
  const int t = threadIdx.x;
  const int w = t >> 6;
  const int l = t & 63;
  const int quad = l >> 4;
  const int l16 = l & 15;
  const int jtp = w & 1, itq = (w >> 1) & 3;  // S roles (w<8)
  const int itp = w & 3, cs = w >> 2;         // PV roles (all 16)

  const u16* qTf = wsm + (size_t)b * BSTR + QTF;
  const u16* kTf = wsm + (size_t)b * BSTR + KTF;
  const u16* vf = wsm + (size_t)b * BSTR + VF;
  float* obuf = (float*)(wsm + (size_t)b * BSTR);  // aliases q-nat + k-nat (8MB)

  // stage Q frags for this i-block: contiguous 128KB
  {
    const uint4* qsrc = (const uint4*)(qTf + (size_t)i0 * 512);
    uint4* qd = (uint4*)Qf;
#pragma unroll
    for (int r = 0; r < 16; ++r) qd[r * 1024 + t] = qsrc[r * 1024 + t];
  }

  float m_st[2] = {-1e30f, -1e30f};
  float l_st[2] = {0.f, 0.f};
  f32x4 oacc[2][8];
#pragma unroll
  for (int b2 = 0; b2 < 2; ++b2)
#pragma unroll
    for (int ct = 0; ct < 8; ++ct) oacc[b2][ct] = (f32x4){0.f, 0.f, 0.f, 0.f};

  __syncthreads();

  for (int j0 = 0; j0 < NN; j0 += 64) {
    float mx[2] = {-1e30f, -1e30f};
    f32x4 sa[2][2];
    if (w < 8) {
#pragma unroll
      for (int a = 0; a < 2; ++a)
#pragma unroll
        for (int b2 = 0; b2 < 2; ++b2) sa[a][b2] = (f32x4){0.f, 0.f, 0.f, 0.f};
      const u16* kb0 = kTf + (size_t)((j0 >> 4) + 2 * jtp) * 8192;  // jtile*16*512
      const u16* kb1 = kb0 + 8192;
      const u16* qb0 = Qf + (itq * 2) * 8192;
      const u16* qb1 = qb0 + 8192;
#pragma unroll 4
      for (int kc = 0; kc < 16; ++kc) {
        bf16x8 a0 = *(const bf16x8*)(kb0 + kc * 512 + l * 8);
        bf16x8 a1 = *(const bf16x8*)(kb1 + kc * 512 + l * 8);
        bf16x8 q0 = *(const bf16x8*)(qb0 + kc * 512 + l * 8);
        bf16x8 q1 = *(const bf16x8*)(qb1 + kc * 512 + l * 8);
        sa[0][0] = __builtin_amdgcn_mfma_f32_16x16x32_bf16(a0, q0, sa[0][0], 0, 0, 0);
        sa[0][1] = __builtin_amdgcn_mfma_f32_16x16x32_bf16(a0, q1, sa[0][1], 0, 0, 0);
        sa[1][0] = __builtin_amdgcn_mfma_f32_16x16x32_bf16(a1, q0, sa[1][0], 0, 0, 0);
        sa[1][1] = __builtin_amdgcn_mfma_f32_16x16x32_bf16(a1, q1, sa[1][1], 0, 0, 0);
      }
      // local max over this wave's 2 jt-tiles (scaled domain)
#pragma unroll
      for (int b2 = 0; b2 < 2; ++b2) {
        float v = -1e30f;
#pragma unroll
        for (int a = 0; a < 2; ++a)
#pragma unroll
          for (int r = 0; r < 4; ++r) v = fmaxf(v, sa[a][b2][r]);
        v *= SCALE;
        v = fmaxf(v, __shfl_xor(v, 16, 64));
        v = fmaxf(v, __shfl_xor(v, 32, 64));
        mx[b2] = v;
      }
      if (l < 16) { mbuf[w][0][l16] = mx[0]; mbuf[w][1][l16] = mx[1]; }
    }
    __syncthreads();  // B_a: partner max visible
    float alpha[2] = {1.f, 1.f};
    float lloc[2] = {0.f, 0.f};
    if (w < 8) {
#pragma unroll
      for (int b2 = 0; b2 < 2; ++b2) {
        const float pm = mbuf[w ^ 1][b2][l16];
        const float mnew = fmaxf(m_st[b2], fmaxf(mx[b2], pm));
        alpha[b2] = __expf(m_st[b2] - mnew);
        m_st[b2] = mnew;
      }
      if (jtp == 0 && l < 32) {
        const int bb = l >> 4;
        alpha_s[(itq * 2 + bb) * 16 + l16] = alpha[bb];
      }
      // P = exp(s*SCALE - m), pack bf16 into A-frag layout
#pragma unroll
      for (int a = 0; a < 2; ++a) {
        const int jtl = 2 * jtp + a;
        const int jg0 = jtl * 16 + quad * 4;  // j-local in [0,64)
        const int kjl = jg0 >> 5;
        const int jg = jg0 & 31;
#pragma unroll
        for (int b2 = 0; b2 < 2; ++b2) {
          float p0 = __expf(fmaf(sa[a][b2][0], SCALE, -m_st[b2]));
          float p1 = __expf(fmaf(sa[a][b2][1], SCALE, -m_st[b2]));
          float p2 = __expf(fmaf(sa[a][b2][2], SCALE, -m_st[b2]));
          float p3 = __expf(fmaf(sa[a][b2][3], SCALE, -m_st[b2]));
          lloc[b2] += (p0 + p1) + (p2 + p3);
          const int lanep = l16 + 16 * ((jg >> 3) & 3);
          *(u64*)(Pf + ((itq * 2 + b2) * 2 + kjl) * 512 + lanep * 8 + (jg & 7)) =
              pack4bf(p0, p1, p2, p3);
        }
      }
#pragma unroll
      for (int b2 = 0; b2 < 2; ++b2) {
        float v = lloc[b2];
        v += __shfl_xor(v, 16, 64);
        v += __shfl_xor(v, 32, 64);
        lloc[b2] = v;
      }
      if (l < 16) { lbuf[w][0][l16] = lloc[0]; lbuf[w][1][l16] = lloc[1]; }
    }
    __syncthreads();  // B_b: P + alpha + partner l visible
    if (w < 8) {
#pragma unroll
      for (int b2 = 0; b2 < 2; ++b2)
        l_st[b2] = l_st[b2] * alpha[b2] + lloc[b2] + lbuf[w ^ 1][b2][l16];
    }
    // ---- PV: all 16 waves; wave = (itp: it-pair, cs: 8 c-tiles) ----
    float4 al[2];
    al[0] = *(const float4*)&alpha_s[(itp * 2 + 0) * 16 + quad * 4];
    al[1] = *(const float4*)&alpha_s[(itp * 2 + 1) * 16 + quad * 4];
#pragma unroll
    for (int b2 = 0; b2 < 2; ++b2)
#pragma unroll
      for (int ct = 0; ct < 8; ++ct) {
        oacc[b2][ct][0] *= al[b2].x;
        oacc[b2][ct][1] *= al[b2].y;
        oacc[b2][ct][2] *= al[b2].z;
        oacc[b2][ct][3] *= al[b2].w;
      }
    bf16x8 pa[2][2];
#pragma unroll
    for (int b2 = 0; b2 < 2; ++b2)
#pragma unroll
      for (int kjl = 0; kjl < 2; ++kjl)
        pa[b2][kjl] = *(const bf16x8*)(Pf + ((itp * 2 + b2) * 2 + kjl) * 512 + l * 8);
    const u16* vbase = vf + (size_t)(j0 >> 5) * 32 * 512;
#pragma unroll 2
    for (int ct = 0; ct < 8; ++ct) {
      const int ctg = cs * 8 + ct;
      bf16x8 v0 = *(const bf16x8*)(vbase + (size_t)ctg * 512 + l * 8);
      bf16x8 v1 = *(const bf16x8*)(vbase + (size_t)(32 + ctg) * 512 + l * 8);
      oacc[0][ct] = __builtin_amdgcn_mfma_f32_16x16x32_bf16(pa[0][0], v0, oacc[0][ct], 0, 0, 0);
      oacc[0][ct] = __builtin_amdgcn_mfma_f32_16x16x32_bf16(pa[0][1], v1, oacc[0][ct], 0, 0, 0);
      oacc[1][ct] = __builtin_amdgcn_mfma_f32_16x16x32_bf16(pa[1][0], v0, oacc[1][ct], 0, 0, 0);
      oacc[1][ct] = __builtin_amdgcn_mfma_f32_16x16x32_bf16(pa[1][1], v1, oacc[1][ct], 0, 0, 0);
    }
    __syncthreads();  // B1: Pf/mbuf/alpha_s reusable next step
  }

  // ---- epilogue: 1/l, then O through LDS for coalesced store ----
  if (w < 8 && l < 32) {
    const int bb = l >> 4;
    invl_s[(itq * 2 + bb) * 16 + l16] = 1.0f / l_st[bb];
  }
  __syncthreads();
  float4 il[2];
  il[0] = *(const float4*)&invl_s[(itp * 2 + 0) * 16 + quad * 4];
  il[1] = *(const float4*)&invl_s[(itp * 2 + 1) * 16 + quad * 4];
#pragma unroll
  for (int b2 = 0; b2 < 2; ++b2)
#pragma unroll
    for (int ct = 0; ct < 8; ++ct) {
      oacc[b2][ct][0] *= il[b2].x;
      oacc[b2][ct][1] *= il[b2].y;
      oacc[b2][ct][2] *= il[b2].z;
      oacc[b2][ct][3] *= il[b2].w;
    }
  float* Of = (float*)Qf;  // 256 rows x 128 floats = 128KB
  for (int chunk = 0; chunk < 2; ++chunk) {
    if ((cs >> 1) == chunk) {
#pragma unroll
      for (int b2 = 0; b2 < 2; ++b2)
#pragma unroll
        for (int ct = 0; ct < 8; ++ct) {
          const int c_loc = (cs & 1) * 128 + ct * 16 + l16;
          const int irow = (itp * 2 + b2) * 16 + quad * 4;
          float* d = Of + c_loc * 128 + irow;
          d[0] = oacc[b2][ct][0];
          d[1] = oacc[b2][ct][1];
          d[2] = oacc[b2][ct][2];
          d[3] = oacc[b2][ct][3];
        }
    }
    __syncthreads();
#pragma unroll
    for (int p = 0; p < 8; ++p) {
      const int c_loc = p * 32 + (t >> 5);
      const int i4 = (t & 31) * 4;
      float4 v = *(const float4*)(Of + c_loc * 128 + i4);
      *(float4*)(obuf + (size_t)(chunk * 256 + c_loc) * NN + i0 + i4) = v;
    }
    __syncthreads();
  }
}

// ------------- output projection + bias + residual -------------
__global__ __launch_bounds__(256) void proj_kernel(
    const u16* __restrict__ wsm, const float* __restrict__ wout,
    const float* __restrict__ bout, const float* __restrict__ x,
    float* __restrict__ out) {
  __shared__ __align__(16) float Wt[16][68];
  __shared__ __align__(16) float Ht[16][68];
  const int b = blockIdx.z;
  const int o0 = blockIdx.y * 64;
  const int n0 = blockIdx.x * 64;
  const int t = threadIdx.x;
  const int to = (t >> 4) * 4;
  const int tn = (t & 15) * 4;
  const int wo = t >> 2;
  const int wk = (t & 3) * 4;
  const int xc = t >> 4;
  const int xn = (t & 15) * 4;
  const float* ob = (const float*)(wsm + (size_t)b * BSTR);
  float acc[4][4] = {{0.f}};
  for (int kk = 0; kk < CC; kk += 16) {
    float4 wv = *(const float4*)(wout + (size_t)(o0 + wo) * CC + kk + wk);
    float4 hv = *(const float4*)(ob + (size_t)(kk + xc) * NN + n0 + xn);
    __syncthreads();
    Wt[wk + 0][wo] = wv.x;
    Wt[wk + 1][wo] = wv.y;
    Wt[wk + 2][wo] = wv.z;
    Wt[wk + 3][wo] = wv.w;
    *(float4*)&Ht[xc][xn] = hv;
    __syncthreads();
#pragma unroll
    for (int k = 0; k < 16; ++k) {
      float4 w4 = *(const float4*)&Wt[k][to];
      float4 h4 = *(const float4*)&Ht[k][tn];
      acc[0][0] = fmaf(w4.x, h4.x, acc[0][0]);
      acc[0][1] = fmaf(w4.x, h4.y, acc[0][1]);
      acc[0][2] = fmaf(w4.x, h4.z, acc[0][2]);
      acc[0][3] = fmaf(w4.x, h4.w, acc[0][3]);
      acc[1][0] = fmaf(w4.y, h4.x, acc[1][0]);
      acc[1][1] = fmaf(w4.y, h4.y, acc[1][1]);
      acc[1][2] = fmaf(w4.y, h4.z, acc[1][2]);
      acc[1][3] = fmaf(w4.y, h4.w, acc[1][3]);
      acc[2][0] = fmaf(w4.z, h4.x, acc[2][0]);
      acc[2][1] = fmaf(w4.z, h4.y, acc[2][1]);
      acc[2][2] = fmaf(w4.z, h4.z, acc[2][2]);
      acc[2][3] = fmaf(w4.z, h4.w, acc[2][3]);
      acc[3][0] = fmaf(w4.w, h4.x, acc[3][0]);
      acc[3][1] = fmaf(w4.w, h4.y, acc[3][1]);
      acc[3][2] = fmaf(w4.w, h4.z, acc[3][2]);
      acc[3][3] = fmaf(w4.w, h4.w, acc[3][3]);
    }
  }
#pragma unroll
  for (int i = 0; i < 4; ++i) {
    const int o = o0 + to + i;
    const float bias = bout[o];
    const size_t idx = ((size_t)b * CC + o) * NN + n0 + tn;
    float4 xv = *(const float4*)(x + idx);
    float4 r;
    r.x = acc[i][0] + bias + xv.x;
    r.y = acc[i][1] + bias + xv.y;
    r.z = acc[i][2] + bias + xv.z;
    r.w = acc[i][3] + bias + xv.w;
    *(float4*)(out + idx) = r;
  }
}

extern "C" void kernel_launch(void* const* d_in, const int* in_sizes, int n_in,
                              void* d_out, int out_size, void* d_ws, size_t ws_size,
                              hipStream_t stream) {
  const float* x = (const float*)d_in[0];
  const float* gamma = (const float*)d_in[1];
  const float* beta = (const float*)d_in[2];
  const float* wqkv = (const float*)d_in[3];
  const float* bqkv = (const float*)d_in[4];
  const float* wout = (const float*)d_in[5];
  const float* bout = (const float*)d_in[6];
  float* out = (float*)d_out;

  char* ws = (char*)d_ws;
  float* stats = (float*)ws;           // 2KB
  u16* wsm = (u16*)(ws + 4096);        // 8 x 20MB = 160MB

  gn_stats_kernel<<<BB * GG, 256, 0, stream>>>(x, stats);
  qkv_gemm_kernel<<<dim3(NN / 64, 1536 / 64, BB), 256, 0, stream>>>(
      x, gamma, beta, wqkv, bqkv, stats, wsm);
  pack_qk_kernel<<<dim3(NN / 64, CC / 64, BB * 2), 256, 0, stream>>>(wsm);
  attn_mfma_kernel<<<dim3(NN / 128, BB), 1024, 0, stream>>>(wsm);
  proj_kernel<<<dim3(NN / 64, CC / 64, BB), 256, 0, stream>>>(wsm, wout, bout, x, out);
}